// Round 10
// baseline (265.427 us; speedup 1.0000x reference)
//
#include <hip/hip_runtime.h>
#include <hip/hip_bf16.h>
#include <math.h>

#define FDIM 256
#define CAP 64
#define NGRAPH 8
#define GMAX_BLOCKS 64
#define FINAL_BLOCKS 512

typedef __attribute__((ext_vector_type(8))) short bf16x8;
typedef __attribute__((ext_vector_type(4))) float f32x4;

__device__ __forceinline__ unsigned enc_f(float x){
  unsigned u = __float_as_uint(x);
  return (u >> 31) ? ~u : (u | 0x80000000u);
}
__device__ __forceinline__ float dec_f(unsigned u){
  return (u >> 31) ? __uint_as_float(u & 0x7FFFFFFFu) : __uint_as_float(~u);
}

__device__ __forceinline__ unsigned short f2bf(float f){
  unsigned u = __float_as_uint(f);
  unsigned r = (u + 0x7FFFu + ((u >> 16) & 1u)) >> 16;
  return (unsigned short)r;
}
__device__ __forceinline__ float bf2f(unsigned short h){
  return __uint_as_float(((unsigned)h) << 16);
}
__device__ __forceinline__ unsigned pk2(float a, float b){
  return (unsigned)f2bf(a) | ((unsigned)f2bf(b) << 16);
}
__device__ __forceinline__ float bfu_lo(unsigned u){ return __uint_as_float(u << 16); }
__device__ __forceinline__ float bfu_hi(unsigned u){ return __uint_as_float(u & 0xFFFF0000u); }

// ---------------- init ----------------
__global__ void init_k(int* cnt, float* denom, float* out, int N){
  int i = blockIdx.x * blockDim.x + threadIdx.x;
  if (i < N) cnt[i] = 0;
  if (i < NGRAPH) denom[i] = 0.f;
  if (i < NGRAPH * FDIM) out[i] = 0.f;
}

// ---------------- CSR fill (capped bucket); cnt = true in-degree ----------------
__global__ void csr_k(const int* __restrict__ src, const int* __restrict__ dst,
                      int* __restrict__ cnt, int* __restrict__ col, int E){
  int e = blockIdx.x * blockDim.x + threadIdx.x;
  if (e < E){
    int d = dst[e];
    int pos = atomicAdd(&cnt[d], 1);
    if (pos < CAP) col[(size_t)d * CAP + pos] = src[e];
  }
}

// ---------------- dinv from cnt (deg = cnt + 1 self-loop) ----------------
__global__ void dinv_k(const int* __restrict__ cnt, float* __restrict__ dinv, int N){
  int i = blockIdx.x * blockDim.x + threadIdx.x;
  if (i < N) dinv[i] = rsqrtf((float)(cnt[i] + 1));
}

// ---------------- W transpose+bf16: Wt[n][k] = bf16(W[k][n]) ----------------
template<int K>
__global__ void wconv_k(const float* __restrict__ W, unsigned short* __restrict__ Wt){
  int idx = blockIdx.x * 256 + threadIdx.x;
  if (idx >= K * 256) return;
  int k = idx >> 8, n = idx & 255;
  Wt[(size_t)n * K + k] = f2bf(W[idx]);
}

// ---------------- pure-bf16 MFMA GEMM, register-staged pipelined ----------------
template<int K, bool A_FP32>
__global__ __launch_bounds__(512) void gemm_k(const void* __restrict__ Av,
                                              const unsigned short* __restrict__ Bt,
                                              unsigned short* __restrict__ C, int M){
  __shared__ unsigned short As[128 * 64];   // 16 KB
  __shared__ unsigned short Bs[256 * 64];   // 32 KB
  const int tid = threadIdx.x;
  const int lane = tid & 63, wid = tid >> 6;
  const int wr = wid >> 2, wc = wid & 3;    // 2 x 4 wave grid
  const int m0 = blockIdx.x * 128;
  f32x4 acc[4][4] = {};

  float4 arf0, arf1, arf2, arf3;
  uint4  arb0, arb1;
  uint4  brg0, brg1, brg2, brg3;

  const int rA0 = tid >> 3,          kqA0 = tid & 7;
  const int rA1 = (512 + tid) >> 3,  kqA1 = tid & 7;

  auto issue = [&](int k0){
    if (A_FP32){
      const float* A = (const float*)Av;
      const float* p0 = A + (size_t)min(m0 + rA0, M - 1) * K + k0 + kqA0 * 8;
      const float* p1 = A + (size_t)min(m0 + rA1, M - 1) * K + k0 + kqA1 * 8;
      arf0 = *(const float4*)p0; arf1 = *(const float4*)(p0 + 4);
      arf2 = *(const float4*)p1; arf3 = *(const float4*)(p1 + 4);
    } else {
      const unsigned short* A = (const unsigned short*)Av;
      arb0 = *(const uint4*)(A + (size_t)min(m0 + rA0, M - 1) * K + k0 + kqA0 * 8);
      arb1 = *(const uint4*)(A + (size_t)min(m0 + rA1, M - 1) * K + k0 + kqA1 * 8);
    }
    {
      int n0 = tid >> 3, n1 = (512 + tid) >> 3, n2 = (1024 + tid) >> 3, n3 = (1536 + tid) >> 3;
      int kq = tid & 7;
      brg0 = *(const uint4*)(Bt + (size_t)n0 * K + k0 + kq * 8);
      brg1 = *(const uint4*)(Bt + (size_t)n1 * K + k0 + kq * 8);
      brg2 = *(const uint4*)(Bt + (size_t)n2 * K + k0 + kq * 8);
      brg3 = *(const uint4*)(Bt + (size_t)n3 * K + k0 + kq * 8);
    }
  };

  auto writeLDS = [&](){
    int kq = tid & 7;
    {
      uint4 u0, u1;
      if (A_FP32){
        u0.x = pk2(arf0.x, arf0.y); u0.y = pk2(arf0.z, arf0.w);
        u0.z = pk2(arf1.x, arf1.y); u0.w = pk2(arf1.z, arf1.w);
        u1.x = pk2(arf2.x, arf2.y); u1.y = pk2(arf2.z, arf2.w);
        u1.z = pk2(arf3.x, arf3.y); u1.w = pk2(arf3.z, arf3.w);
      } else { u0 = arb0; u1 = arb1; }
      *(uint4*)((char*)As + ((rA0 * 128 + kq * 16) ^ ((rA0 & 7) << 4))) = u0;
      *(uint4*)((char*)As + ((rA1 * 128 + kq * 16) ^ ((rA1 & 7) << 4))) = u1;
    }
    {
      int n0 = tid >> 3, n1 = (512 + tid) >> 3, n2 = (1024 + tid) >> 3, n3 = (1536 + tid) >> 3;
      *(uint4*)((char*)Bs + ((n0 * 128 + kq * 16) ^ ((n0 & 7) << 4))) = brg0;
      *(uint4*)((char*)Bs + ((n1 * 128 + kq * 16) ^ ((n1 & 7) << 4))) = brg1;
      *(uint4*)((char*)Bs + ((n2 * 128 + kq * 16) ^ ((n2 & 7) << 4))) = brg2;
      *(uint4*)((char*)Bs + ((n3 * 128 + kq * 16) ^ ((n3 & 7) << 4))) = brg3;
    }
  };

  issue(0);
  for (int k0 = 0; k0 < K; k0 += 64){
    writeLDS();
    __syncthreads();
    if (k0 + 64 < K) issue(k0 + 64);

    #pragma unroll
    for (int kk = 0; kk < 64; kk += 32){
      bf16x8 af[4], bfr[4];
      int kb = kk * 2 + ((lane >> 4) << 4);
      #pragma unroll
      for (int mi = 0; mi < 4; ++mi){
        int r = wr * 64 + mi * 16 + (lane & 15);
        af[mi] = *(bf16x8*)((char*)As + ((r * 128 + kb) ^ ((r & 7) << 4)));
      }
      #pragma unroll
      for (int ni = 0; ni < 4; ++ni){
        int n = wc * 64 + ni * 16 + (lane & 15);
        bfr[ni] = *(bf16x8*)((char*)Bs + ((n * 128 + kb) ^ ((n & 7) << 4)));
      }
      #pragma unroll
      for (int mi = 0; mi < 4; ++mi)
        #pragma unroll
        for (int ni = 0; ni < 4; ++ni)
          acc[mi][ni] = __builtin_amdgcn_mfma_f32_16x16x32_bf16(af[mi], bfr[ni], acc[mi][ni], 0, 0, 0);
    }
    __syncthreads();
  }

  #pragma unroll
  for (int mi = 0; mi < 4; ++mi){
    #pragma unroll
    for (int reg = 0; reg < 4; ++reg){
      int row = m0 + wr * 64 + mi * 16 + ((lane >> 4) << 2) + reg;
      if (row < M){
        #pragma unroll
        for (int ni = 0; ni < 4; ++ni){
          int colc = wc * 64 + ni * 16 + (lane & 15);
          C[(size_t)row * FDIM + colc] = f2bf(acc[mi][ni][reg]);
        }
      }
    }
  }
}

// ---------------- aggregation: 4 waves/block, 2 edges per wave-load ----------------
// Wave = one node. Halves (32 lanes) each gather a different edge row at 16B/lane.
template<bool OUT_BF16, bool GATE>
__global__ __launch_bounds__(256) void agg_k(const unsigned short* __restrict__ xw,
                                             const float* __restrict__ dinv,
                                             const int* __restrict__ col,
                                             const int* __restrict__ cnt,
                                             const float* __restrict__ bias,
                                             void* __restrict__ outv,
                                             const float* __restrict__ gw,
                                             const float* __restrict__ gb,
                                             float* __restrict__ gate, int N){
  int node = blockIdx.x * 4 + (threadIdx.x >> 6);
  if (node >= N) return;
  int lane = threadIdx.x & 63;
  int half = lane >> 5;        // 0/1: which edge of the pair
  int hl = lane & 31;          // feature block: features hl*8 .. hl*8+7

  float di = dinv[node];
  int n = min(cnt[node], CAP);
  int s = 0; float w = 0.f;
  if (lane < n){ s = col[(size_t)node * CAP + lane]; w = di * dinv[s]; }

  float a0=0.f,a1=0.f,a2=0.f,a3=0.f,a4=0.f,a5=0.f,a6=0.f,a7=0.f;
  // self term: half 0 only (added once after cross-half reduce)
  if (half == 0){
    uint4 v = *(const uint4*)(xw + (size_t)node * FDIM + hl * 8);
    float sw = di * di;
    a0 = sw * bfu_lo(v.x); a1 = sw * bfu_hi(v.x);
    a2 = sw * bfu_lo(v.y); a3 = sw * bfu_hi(v.y);
    a4 = sw * bfu_lo(v.z); a5 = sw * bfu_hi(v.z);
    a6 = sw * bfu_lo(v.w); a7 = sw * bfu_hi(v.w);
  }

  // pipeline: chunks of 4 pair-steps = 8 edges; double-buffered
  uint4 bufA[4], bufB[4];
  int ns = (n + 1) >> 1;        // pair steps
  int nc = (ns + 3) >> 2;       // chunks

  auto loadChunk = [&](uint4 (&buf)[4], int c){
    #pragma unroll
    for (int j = 0; j < 4; ++j){
      int e = (c * 4 + j) * 2 + half;      // e < 64 always (nc<=8)
      int se = __shfl(s, e);
      buf[j] = *(const uint4*)(xw + (size_t)se * FDIM + hl * 8);
    }
  };
  auto consChunk = [&](uint4 (&buf)[4], int c){
    #pragma unroll
    for (int j = 0; j < 4; ++j){
      int e = (c * 4 + j) * 2 + half;
      float we = __shfl(w, e);
      uint4 v = buf[j];
      a0 += we * bfu_lo(v.x); a1 += we * bfu_hi(v.x);
      a2 += we * bfu_lo(v.y); a3 += we * bfu_hi(v.y);
      a4 += we * bfu_lo(v.z); a5 += we * bfu_hi(v.z);
      a6 += we * bfu_lo(v.w); a7 += we * bfu_hi(v.w);
    }
  };

  if (nc > 0) loadChunk(bufA, 0);
  for (int c = 0; c < nc; ++c){
    if (c & 1){
      if (c + 1 < nc) loadChunk(bufA, c + 1);
      consChunk(bufB, c);
    } else {
      if (c + 1 < nc) loadChunk(bufB, c + 1);
      consChunk(bufA, c);
    }
  }

  // cross-half combine: lane hl and lane hl+32 hold same features
  a0 += __shfl_xor(a0, 32); a1 += __shfl_xor(a1, 32);
  a2 += __shfl_xor(a2, 32); a3 += __shfl_xor(a3, 32);
  a4 += __shfl_xor(a4, 32); a5 += __shfl_xor(a5, 32);
  a6 += __shfl_xor(a6, 32); a7 += __shfl_xor(a7, 32);

  float4 bv0 = *(const float4*)(bias + hl * 8);
  float4 bv1 = *(const float4*)(bias + hl * 8 + 4);
  a0 = fmaxf(a0 + bv0.x, 0.f); a1 = fmaxf(a1 + bv0.y, 0.f);
  a2 = fmaxf(a2 + bv0.z, 0.f); a3 = fmaxf(a3 + bv0.w, 0.f);
  a4 = fmaxf(a4 + bv1.x, 0.f); a5 = fmaxf(a5 + bv1.y, 0.f);
  a6 = fmaxf(a6 + bv1.z, 0.f); a7 = fmaxf(a7 + bv1.w, 0.f);

  if (half == 0){
    if (OUT_BF16){
      uint4 r;
      r.x = pk2(a0, a1); r.y = pk2(a2, a3);
      r.z = pk2(a4, a5); r.w = pk2(a6, a7);
      *(uint4*)((unsigned short*)outv + (size_t)node * FDIM + hl * 8) = r;
    } else {
      float* po = (float*)outv + (size_t)node * FDIM + hl * 8;
      *(float4*)po       = make_float4(a0, a1, a2, a3);
      *(float4*)(po + 4) = make_float4(a4, a5, a6, a7);
    }
  }
  if (GATE){
    float4 g0 = *(const float4*)(gw + hl * 8);
    float4 g1 = *(const float4*)(gw + hl * 8 + 4);
    float val = a0*g0.x + a1*g0.y + a2*g0.z + a3*g0.w
              + a4*g1.x + a5*g1.y + a6*g1.z + a7*g1.w;
    #pragma unroll
    for (int off = 16; off; off >>= 1) val += __shfl_xor(val, off);  // reduce within half
    if (lane == 0) gate[node] = val + gb[0];
  }
}

// ---------------- gmax: per-block partial segment max of gate ----------------
__global__ __launch_bounds__(256) void gmax_k(const float* __restrict__ gate,
                                              const int* __restrict__ batch,
                                              unsigned* __restrict__ pmax, int N){
  __shared__ unsigned smax[NGRAPH];
  int tid = threadIdx.x;
  if (tid < NGRAPH) smax[tid] = 0u;
  __syncthreads();
  int chunk = (N + gridDim.x - 1) / gridDim.x;
  int begin = blockIdx.x * chunk;
  int end = min(begin + chunk, N);
  int curg = -1; unsigned curm = 0u;
  for (int i = begin + tid; i < end; i += 256){
    int g = batch[i];
    unsigned v = enc_f(gate[i]);
    if (g != curg){
      if (curg >= 0) atomicMax(&smax[curg], curm);
      curg = g; curm = v;
    } else if (v > curm) curm = v;
  }
  if (curg >= 0) atomicMax(&smax[curg], curm);
  __syncthreads();
  if (tid < NGRAPH) pmax[blockIdx.x * NGRAPH + tid] = smax[tid];
}

// ---------------- denom: reduce pmax, e=exp(gate-gmax), segment sum ----------------
__global__ __launch_bounds__(256) void denom_k(float* __restrict__ gate,
                                               const int* __restrict__ batch,
                                               const unsigned* __restrict__ pmax,
                                               float* __restrict__ denom, int N){
  __shared__ unsigned sge[NGRAPH];
  __shared__ float gm[NGRAPH];
  __shared__ float dsum[NGRAPH];
  int tid = threadIdx.x;
  if (tid < NGRAPH){ sge[tid] = 0u; dsum[tid] = 0.f; }
  __syncthreads();
  for (int j = tid; j < GMAX_BLOCKS * NGRAPH; j += 256)
    atomicMax(&sge[j & (NGRAPH - 1)], pmax[j]);
  __syncthreads();
  if (tid < NGRAPH){
    unsigned u = sge[tid];
    gm[tid] = (u == 0u) ? 0.f : dec_f(u);
  }
  __syncthreads();
  int chunk = (N + gridDim.x - 1) / gridDim.x;
  int begin = blockIdx.x * chunk;
  int end = min(begin + chunk, N);
  int curg = -1; float cursum = 0.f;
  for (int i = begin + tid; i < end; i += 256){
    int g = batch[i];
    float e = expf(gate[i] - gm[g]);
    gate[i] = e;
    if (g != curg){
      if (curg >= 0) atomicAdd(&dsum[curg], cursum);
      curg = g; cursum = e;
    } else cursum += e;
  }
  if (curg >= 0) atomicAdd(&dsum[curg], cursum);
  __syncthreads();
  if (tid < NGRAPH && dsum[tid] != 0.f) atomicAdd(&denom[tid], dsum[tid]);
}

// ---------------- final: out[g] += (e_i/denom_g) * h2[i], wave-parallel ----------------
__global__ __launch_bounds__(256) void final_k(const float* __restrict__ h,
                                               const float* __restrict__ e,
                                               const int* __restrict__ batch,
                                               const float* __restrict__ denom,
                                               float* __restrict__ out, int N){
  __shared__ float sacc[NGRAPH * FDIM];   // 8 KB
  int tid = threadIdx.x;
  #pragma unroll
  for (int j = tid; j < NGRAPH * FDIM; j += 256) sacc[j] = 0.f;
  __syncthreads();
  int lane = tid & 63, w = tid >> 6;
  int chunk = (N + gridDim.x - 1) / gridDim.x;
  int begin = blockIdx.x * chunk;
  int end = min(begin + chunk, N);
  float4 acc = make_float4(0.f, 0.f, 0.f, 0.f);
  int curg = -1;
  for (int i = begin + w; i < end; i += 4){
    int g = batch[i];
    if (g != curg){
      if (curg >= 0){
        atomicAdd(&sacc[curg * FDIM + lane * 4 + 0], acc.x);
        atomicAdd(&sacc[curg * FDIM + lane * 4 + 1], acc.y);
        atomicAdd(&sacc[curg * FDIM + lane * 4 + 2], acc.z);
        atomicAdd(&sacc[curg * FDIM + lane * 4 + 3], acc.w);
        acc = make_float4(0.f, 0.f, 0.f, 0.f);
      }
      curg = g;
    }
    float alpha = e[i] / denom[g];
    float4 v = *(const float4*)(h + (size_t)i * FDIM + lane * 4);
    acc.x += alpha * v.x; acc.y += alpha * v.y;
    acc.z += alpha * v.z; acc.w += alpha * v.w;
  }
  if (curg >= 0){
    atomicAdd(&sacc[curg * FDIM + lane * 4 + 0], acc.x);
    atomicAdd(&sacc[curg * FDIM + lane * 4 + 1], acc.y);
    atomicAdd(&sacc[curg * FDIM + lane * 4 + 2], acc.z);
    atomicAdd(&sacc[curg * FDIM + lane * 4 + 3], acc.w);
  }
  __syncthreads();
  if (begin < end){
    int g0 = batch[begin], g1 = batch[end - 1];
    for (int g = g0; g <= g1; ++g){
      float v = sacc[g * FDIM + tid];
      if (v != 0.f) atomicAdd(&out[g * FDIM + tid], v);
    }
  }
}

extern "C" void kernel_launch(void* const* d_in, const int* in_sizes, int n_in,
                              void* d_out, int out_size, void* d_ws, size_t ws_size,
                              hipStream_t stream){
  const float* x     = (const float*)d_in[0];
  const int*   ei    = (const int*)  d_in[1];
  const int*   batch = (const int*)  d_in[2];
  const float* W1    = (const float*)d_in[3];
  const float* b1    = (const float*)d_in[4];
  const float* W2    = (const float*)d_in[5];
  const float* b2    = (const float*)d_in[6];
  const float* gw    = (const float*)d_in[7];
  const float* gb    = (const float*)d_in[8];
  float* out = (float*)d_out;

  const int N = in_sizes[2];
  const int E = in_sizes[1] / 2;
  const int* src = ei;
  const int* dst = ei + E;

  size_t off = 0;
  auto carve = [&](size_t bytes) -> void* {
    void* p = (char*)d_ws + off;
    off += (bytes + 255) / 256 * 256;
    return p;
  };
  float*          h     = (float*)         carve((size_t)N * FDIM * 4);  // fp32 h2
  unsigned short* h1b   = (unsigned short*)carve((size_t)N * FDIM * 2);  // bf16 h1
  unsigned short* xwb   = (unsigned short*)carve((size_t)N * FDIM * 2);  // bf16 xW
  int*            cnt   = (int*)           carve((size_t)N * 4);
  float*          dinv  = (float*)         carve((size_t)N * 4);
  int*            col   = (int*)           carve((size_t)N * CAP * 4);
  float*          gate  = (float*)         carve((size_t)N * 4);
  unsigned*       pmax  = (unsigned*)      carve(GMAX_BLOCKS * NGRAPH * 4);
  float*          denom = (float*)         carve(NGRAPH * 4);
  unsigned short* Wt1   = (unsigned short*)carve((size_t)256 * 512 * 2);
  unsigned short* Wt2   = (unsigned short*)carve((size_t)256 * 256 * 2);
  (void)ws_size; (void)n_in; (void)out_size;

  const int TB = 256;
  init_k<<<(N + TB - 1) / TB, TB, 0, stream>>>(cnt, denom, out, N);
  csr_k<<<(E + TB - 1) / TB, TB, 0, stream>>>(src, dst, cnt, col, E);
  dinv_k<<<(N + TB - 1) / TB, TB, 0, stream>>>(cnt, dinv, N);
  wconv_k<512><<<(512 * 256 + TB - 1) / TB, TB, 0, stream>>>(W1, Wt1);
  wconv_k<256><<<(256 * 256 + TB - 1) / TB, TB, 0, stream>>>(W2, Wt2);

  int gblocks = (N + 127) / 128;
  int ablocks = (N + 3) / 4;
  gemm_k<512, true ><<<gblocks, 512, 0, stream>>>(x,   Wt1, xwb, N);
  agg_k<true,  false><<<ablocks, 256, 0, stream>>>(xwb, dinv, col, cnt, b1, h1b, nullptr, nullptr, nullptr, N);
  gemm_k<256, false><<<gblocks, 512, 0, stream>>>(h1b, Wt2, xwb, N);
  agg_k<false, true ><<<ablocks, 256, 0, stream>>>(xwb, dinv, col, cnt, b2, h, gw, gb, gate, N);

  gmax_k<<<GMAX_BLOCKS, 256, 0, stream>>>(gate, batch, pmax, N);
  denom_k<<<GMAX_BLOCKS, 256, 0, stream>>>(gate, batch, pmax, denom, N);
  final_k<<<FINAL_BLOCKS, 256, 0, stream>>>(h, gate, batch, denom, out, N);
}

// Round 12
// 249.596 us; speedup vs baseline: 1.0634x; 1.0634x over previous
//
#include <hip/hip_runtime.h>
#include <hip/hip_bf16.h>
#include <math.h>

#define FDIM 256
#define CAP 64
#define NGRAPH 8
#define GMAX_BLOCKS 64
#define FINAL_BLOCKS 512

typedef __attribute__((ext_vector_type(8))) short bf16x8;
typedef __attribute__((ext_vector_type(4))) float f32x4;

__device__ __forceinline__ unsigned enc_f(float x){
  unsigned u = __float_as_uint(x);
  return (u >> 31) ? ~u : (u | 0x80000000u);
}
__device__ __forceinline__ float dec_f(unsigned u){
  return (u >> 31) ? __uint_as_float(u & 0x7FFFFFFFu) : __uint_as_float(~u);
}

__device__ __forceinline__ unsigned short f2bf(float f){
  unsigned u = __float_as_uint(f);
  unsigned r = (u + 0x7FFFu + ((u >> 16) & 1u)) >> 16;
  return (unsigned short)r;
}
__device__ __forceinline__ float bf2f(unsigned short h){
  return __uint_as_float(((unsigned)h) << 16);
}
__device__ __forceinline__ unsigned pk2(float a, float b){
  return (unsigned)f2bf(a) | ((unsigned)f2bf(b) << 16);
}

// ---------------- init ----------------
__global__ void init_k(int* cnt, float* denom, float* out, int N){
  int i = blockIdx.x * blockDim.x + threadIdx.x;
  if (i < N) cnt[i] = 0;
  if (i < NGRAPH) denom[i] = 0.f;
  if (i < NGRAPH * FDIM) out[i] = 0.f;
}

// ---------------- CSR fill (capped bucket); cnt = true in-degree ----------------
__global__ void csr_k(const int* __restrict__ src, const int* __restrict__ dst,
                      int* __restrict__ cnt, int* __restrict__ col, int E){
  int e = blockIdx.x * blockDim.x + threadIdx.x;
  if (e < E){
    int d = dst[e];
    int pos = atomicAdd(&cnt[d], 1);
    if (pos < CAP) col[(size_t)d * CAP + pos] = src[e];
  }
}

// ---------------- dinv from cnt (deg = cnt + 1 self-loop) ----------------
__global__ void dinv_k(const int* __restrict__ cnt, float* __restrict__ dinv, int N){
  int i = blockIdx.x * blockDim.x + threadIdx.x;
  if (i < N) dinv[i] = rsqrtf((float)(cnt[i] + 1));
}

// ---------------- W1+W2 transpose+bf16 (merged) ----------------
__global__ void wconv_k(const float* __restrict__ W1, const float* __restrict__ W2,
                        unsigned short* __restrict__ Wt1, unsigned short* __restrict__ Wt2){
  int idx = blockIdx.x * 256 + threadIdx.x;
  if (idx < 512 * 256){
    int k = idx >> 8, n = idx & 255;
    Wt1[(size_t)n * 512 + k] = f2bf(W1[idx]);
  } else {
    int j = idx - 512 * 256;
    if (j < 256 * 256){
      int k = j >> 8, n = j & 255;
      Wt2[(size_t)n * 256 + k] = f2bf(W2[j]);
    }
  }
}

// ---------------- pure-bf16 MFMA GEMM, register-staged pipelined ----------------
template<int K, bool A_FP32>
__global__ __launch_bounds__(512) void gemm_k(const void* __restrict__ Av,
                                              const unsigned short* __restrict__ Bt,
                                              unsigned short* __restrict__ C, int M){
  __shared__ unsigned short As[128 * 64];   // 16 KB
  __shared__ unsigned short Bs[256 * 64];   // 32 KB
  const int tid = threadIdx.x;
  const int lane = tid & 63, wid = tid >> 6;
  const int wr = wid >> 2, wc = wid & 3;    // 2 x 4 wave grid
  const int m0 = blockIdx.x * 128;
  f32x4 acc[4][4] = {};

  float4 arf0, arf1, arf2, arf3;
  uint4  arb0, arb1;
  uint4  brg0, brg1, brg2, brg3;

  const int rA0 = tid >> 3,          kqA0 = tid & 7;
  const int rA1 = (512 + tid) >> 3,  kqA1 = tid & 7;

  auto issue = [&](int k0){
    if (A_FP32){
      const float* A = (const float*)Av;
      const float* p0 = A + (size_t)min(m0 + rA0, M - 1) * K + k0 + kqA0 * 8;
      const float* p1 = A + (size_t)min(m0 + rA1, M - 1) * K + k0 + kqA1 * 8;
      arf0 = *(const float4*)p0; arf1 = *(const float4*)(p0 + 4);
      arf2 = *(const float4*)p1; arf3 = *(const float4*)(p1 + 4);
    } else {
      const unsigned short* A = (const unsigned short*)Av;
      arb0 = *(const uint4*)(A + (size_t)min(m0 + rA0, M - 1) * K + k0 + kqA0 * 8);
      arb1 = *(const uint4*)(A + (size_t)min(m0 + rA1, M - 1) * K + k0 + kqA1 * 8);
    }
    {
      int n0 = tid >> 3, n1 = (512 + tid) >> 3, n2 = (1024 + tid) >> 3, n3 = (1536 + tid) >> 3;
      int kq = tid & 7;
      brg0 = *(const uint4*)(Bt + (size_t)n0 * K + k0 + kq * 8);
      brg1 = *(const uint4*)(Bt + (size_t)n1 * K + k0 + kq * 8);
      brg2 = *(const uint4*)(Bt + (size_t)n2 * K + k0 + kq * 8);
      brg3 = *(const uint4*)(Bt + (size_t)n3 * K + k0 + kq * 8);
    }
  };

  auto writeLDS = [&](){
    int kq = tid & 7;
    {
      uint4 u0, u1;
      if (A_FP32){
        u0.x = pk2(arf0.x, arf0.y); u0.y = pk2(arf0.z, arf0.w);
        u0.z = pk2(arf1.x, arf1.y); u0.w = pk2(arf1.z, arf1.w);
        u1.x = pk2(arf2.x, arf2.y); u1.y = pk2(arf2.z, arf2.w);
        u1.z = pk2(arf3.x, arf3.y); u1.w = pk2(arf3.z, arf3.w);
      } else { u0 = arb0; u1 = arb1; }
      *(uint4*)((char*)As + ((rA0 * 128 + kq * 16) ^ ((rA0 & 7) << 4))) = u0;
      *(uint4*)((char*)As + ((rA1 * 128 + kq * 16) ^ ((rA1 & 7) << 4))) = u1;
    }
    {
      int n0 = tid >> 3, n1 = (512 + tid) >> 3, n2 = (1024 + tid) >> 3, n3 = (1536 + tid) >> 3;
      *(uint4*)((char*)Bs + ((n0 * 128 + kq * 16) ^ ((n0 & 7) << 4))) = brg0;
      *(uint4*)((char*)Bs + ((n1 * 128 + kq * 16) ^ ((n1 & 7) << 4))) = brg1;
      *(uint4*)((char*)Bs + ((n2 * 128 + kq * 16) ^ ((n2 & 7) << 4))) = brg2;
      *(uint4*)((char*)Bs + ((n3 * 128 + kq * 16) ^ ((n3 & 7) << 4))) = brg3;
    }
  };

  issue(0);
  for (int k0 = 0; k0 < K; k0 += 64){
    writeLDS();
    __syncthreads();
    if (k0 + 64 < K) issue(k0 + 64);

    #pragma unroll
    for (int kk = 0; kk < 64; kk += 32){
      bf16x8 af[4], bfr[4];
      int kb = kk * 2 + ((lane >> 4) << 4);
      #pragma unroll
      for (int mi = 0; mi < 4; ++mi){
        int r = wr * 64 + mi * 16 + (lane & 15);
        af[mi] = *(bf16x8*)((char*)As + ((r * 128 + kb) ^ ((r & 7) << 4)));
      }
      #pragma unroll
      for (int ni = 0; ni < 4; ++ni){
        int n = wc * 64 + ni * 16 + (lane & 15);
        bfr[ni] = *(bf16x8*)((char*)Bs + ((n * 128 + kb) ^ ((n & 7) << 4)));
      }
      #pragma unroll
      for (int mi = 0; mi < 4; ++mi)
        #pragma unroll
        for (int ni = 0; ni < 4; ++ni)
          acc[mi][ni] = __builtin_amdgcn_mfma_f32_16x16x32_bf16(af[mi], bfr[ni], acc[mi][ni], 0, 0, 0);
    }
    __syncthreads();
  }

  #pragma unroll
  for (int mi = 0; mi < 4; ++mi){
    #pragma unroll
    for (int reg = 0; reg < 4; ++reg){
      int row = m0 + wr * 64 + mi * 16 + ((lane >> 4) << 2) + reg;
      if (row < M){
        #pragma unroll
        for (int ni = 0; ni < 4; ++ni){
          int colc = wc * 64 + ni * 16 + (lane & 15);
          C[(size_t)row * FDIM + colc] = f2bf(acc[mi][ni][reg]);
        }
      }
    }
  }
}

// ---------------- aggregation: round-9 load pattern, 4 waves/block ----------------
// Wave = one node; lane covers 4 features (uint2 = 4 bf16); 8-deep dbuf pipeline.
template<bool OUT_BF16, bool GATE>
__global__ __launch_bounds__(256) void agg_k(const unsigned short* __restrict__ xw,
                                             const float* __restrict__ dinv,
                                             const int* __restrict__ col,
                                             const int* __restrict__ cnt,
                                             const float* __restrict__ bias,
                                             void* __restrict__ outv,
                                             const float* __restrict__ gw,
                                             const float* __restrict__ gb,
                                             float* __restrict__ gate, int N){
  int node = blockIdx.x * 4 + (threadIdx.x >> 6);
  if (node >= N) return;
  int lane = threadIdx.x & 63;
  float di = dinv[node];
  int n = min(cnt[node], CAP);
  int s = 0; float w = 0.f;
  if (lane < n){ s = col[(size_t)node * CAP + lane]; w = di * dinv[s]; }

  float a0, a1, a2, a3;
  {
    ushort4 v = *(const ushort4*)(xw + (size_t)node * FDIM + lane * 4);
    float sw = di * di;
    a0 = sw * bf2f(v.x); a1 = sw * bf2f(v.y); a2 = sw * bf2f(v.z); a3 = sw * bf2f(v.w);
  }

  uint2 bufA[8], bufB[8];
  int nc = (n + 7) >> 3;            // chunks of 8 edges

  auto loadChunk = [&](uint2 (&buf)[8], int c){
    #pragma unroll
    for (int j = 0; j < 8; ++j){
      int e = c * 8 + j;
      int se = __shfl(s, e);
      buf[j] = *(const uint2*)(xw + (size_t)se * FDIM + lane * 4);
    }
  };
  auto consChunk = [&](uint2 (&buf)[8], int c){
    #pragma unroll
    for (int j = 0; j < 8; ++j){
      int e = c * 8 + j;
      float we = __shfl(w, e);
      ushort4 v = *(ushort4*)&buf[j];
      a0 += we * bf2f(v.x); a1 += we * bf2f(v.y);
      a2 += we * bf2f(v.z); a3 += we * bf2f(v.w);
    }
  };

  if (nc > 0) loadChunk(bufA, 0);
  for (int c = 0; c < nc; ++c){
    if (c & 1){
      if (c + 1 < nc) loadChunk(bufA, c + 1);
      consChunk(bufB, c);
    } else {
      if (c + 1 < nc) loadChunk(bufB, c + 1);
      consChunk(bufA, c);
    }
  }

  float4 bv = *(const float4*)(bias + lane * 4);
  a0 = fmaxf(a0 + bv.x, 0.f); a1 = fmaxf(a1 + bv.y, 0.f);
  a2 = fmaxf(a2 + bv.z, 0.f); a3 = fmaxf(a3 + bv.w, 0.f);
  if (OUT_BF16){
    ushort4 r = make_ushort4(f2bf(a0), f2bf(a1), f2bf(a2), f2bf(a3));
    *(ushort4*)((unsigned short*)outv + (size_t)node * FDIM + lane * 4) = r;
  } else {
    *(float4*)((float*)outv + (size_t)node * FDIM + lane * 4) = make_float4(a0, a1, a2, a3);
  }
  if (GATE){
    float4 g = *(const float4*)(gw + lane * 4);
    float val = a0 * g.x + a1 * g.y + a2 * g.z + a3 * g.w;
    #pragma unroll
    for (int off = 32; off; off >>= 1) val += __shfl_down(val, off);
    if (lane == 0) gate[node] = val + gb[0];
  }
}

// ---------------- gmax: per-block partial segment max of gate ----------------
__global__ __launch_bounds__(256) void gmax_k(const float* __restrict__ gate,
                                              const int* __restrict__ batch,
                                              unsigned* __restrict__ pmax, int N){
  __shared__ unsigned smax[NGRAPH];
  int tid = threadIdx.x;
  if (tid < NGRAPH) smax[tid] = 0u;
  __syncthreads();
  int chunk = (N + gridDim.x - 1) / gridDim.x;
  int begin = blockIdx.x * chunk;
  int end = min(begin + chunk, N);
  int curg = -1; unsigned curm = 0u;
  for (int i = begin + tid; i < end; i += 256){
    int g = batch[i];
    unsigned v = enc_f(gate[i]);
    if (g != curg){
      if (curg >= 0) atomicMax(&smax[curg], curm);
      curg = g; curm = v;
    } else if (v > curm) curm = v;
  }
  if (curg >= 0) atomicMax(&smax[curg], curm);
  __syncthreads();
  if (tid < NGRAPH) pmax[blockIdx.x * NGRAPH + tid] = smax[tid];
}

// ---------------- denom: reduce pmax, e=exp(gate-gmax), segment sum ----------------
__global__ __launch_bounds__(256) void denom_k(float* __restrict__ gate,
                                               const int* __restrict__ batch,
                                               const unsigned* __restrict__ pmax,
                                               float* __restrict__ denom, int N){
  __shared__ unsigned sge[NGRAPH];
  __shared__ float gm[NGRAPH];
  __shared__ float dsum[NGRAPH];
  int tid = threadIdx.x;
  if (tid < NGRAPH){ sge[tid] = 0u; dsum[tid] = 0.f; }
  __syncthreads();
  for (int j = tid; j < GMAX_BLOCKS * NGRAPH; j += 256)
    atomicMax(&sge[j & (NGRAPH - 1)], pmax[j]);
  __syncthreads();
  if (tid < NGRAPH){
    unsigned u = sge[tid];
    gm[tid] = (u == 0u) ? 0.f : dec_f(u);
  }
  __syncthreads();
  int chunk = (N + gridDim.x - 1) / gridDim.x;
  int begin = blockIdx.x * chunk;
  int end = min(begin + chunk, N);
  int curg = -1; float cursum = 0.f;
  for (int i = begin + tid; i < end; i += 256){
    int g = batch[i];
    float e = expf(gate[i] - gm[g]);
    gate[i] = e;
    if (g != curg){
      if (curg >= 0) atomicAdd(&dsum[curg], cursum);
      curg = g; cursum = e;
    } else cursum += e;
  }
  if (curg >= 0) atomicAdd(&dsum[curg], cursum);
  __syncthreads();
  if (tid < NGRAPH && dsum[tid] != 0.f) atomicAdd(&denom[tid], dsum[tid]);
}

// ---------------- final: out[g] += (e_i/denom_g) * h2[i], h2 in bf16 ----------------
__global__ __launch_bounds__(256) void final_k(const unsigned short* __restrict__ h,
                                               const float* __restrict__ e,
                                               const int* __restrict__ batch,
                                               const float* __restrict__ denom,
                                               float* __restrict__ out, int N){
  __shared__ float sacc[NGRAPH * FDIM];   // 8 KB
  int tid = threadIdx.x;
  #pragma unroll
  for (int j = tid; j < NGRAPH * FDIM; j += 256) sacc[j] = 0.f;
  __syncthreads();
  int lane = tid & 63, w = tid >> 6;
  int chunk = (N + gridDim.x - 1) / gridDim.x;
  int begin = blockIdx.x * chunk;
  int end = min(begin + chunk, N);
  float4 acc = make_float4(0.f, 0.f, 0.f, 0.f);
  int curg = -1;
  for (int i = begin + w; i < end; i += 4){
    int g = batch[i];
    if (g != curg){
      if (curg >= 0){
        atomicAdd(&sacc[curg * FDIM + lane * 4 + 0], acc.x);
        atomicAdd(&sacc[curg * FDIM + lane * 4 + 1], acc.y);
        atomicAdd(&sacc[curg * FDIM + lane * 4 + 2], acc.z);
        atomicAdd(&sacc[curg * FDIM + lane * 4 + 3], acc.w);
        acc = make_float4(0.f, 0.f, 0.f, 0.f);
      }
      curg = g;
    }
    float alpha = e[i] / denom[g];
    ushort4 v = *(const ushort4*)(h + (size_t)i * FDIM + lane * 4);
    acc.x += alpha * bf2f(v.x); acc.y += alpha * bf2f(v.y);
    acc.z += alpha * bf2f(v.z); acc.w += alpha * bf2f(v.w);
  }
  if (curg >= 0){
    atomicAdd(&sacc[curg * FDIM + lane * 4 + 0], acc.x);
    atomicAdd(&sacc[curg * FDIM + lane * 4 + 1], acc.y);
    atomicAdd(&sacc[curg * FDIM + lane * 4 + 2], acc.z);
    atomicAdd(&sacc[curg * FDIM + lane * 4 + 3], acc.w);
  }
  __syncthreads();
  if (begin < end){
    int g0 = batch[begin], g1 = batch[end - 1];
    for (int g = g0; g <= g1; ++g){
      float v = sacc[g * FDIM + tid];
      if (v != 0.f) atomicAdd(&out[g * FDIM + tid], v);
    }
  }
}

extern "C" void kernel_launch(void* const* d_in, const int* in_sizes, int n_in,
                              void* d_out, int out_size, void* d_ws, size_t ws_size,
                              hipStream_t stream){
  const float* x     = (const float*)d_in[0];
  const int*   ei    = (const int*)  d_in[1];
  const int*   batch = (const int*)  d_in[2];
  const float* W1    = (const float*)d_in[3];
  const float* b1    = (const float*)d_in[4];
  const float* W2    = (const float*)d_in[5];
  const float* b2    = (const float*)d_in[6];
  const float* gw    = (const float*)d_in[7];
  const float* gb    = (const float*)d_in[8];
  float* out = (float*)d_out;

  const int N = in_sizes[2];
  const int E = in_sizes[1] / 2;
  const int* src = ei;
  const int* dst = ei + E;

  size_t off = 0;
  auto carve = [&](size_t bytes) -> void* {
    void* p = (char*)d_ws + off;
    off += (bytes + 255) / 256 * 256;
    return p;
  };
  unsigned short* h     = (unsigned short*)carve((size_t)N * FDIM * 2);  // bf16 h2
  unsigned short* h1b   = (unsigned short*)carve((size_t)N * FDIM * 2);  // bf16 h1
  unsigned short* xwb   = (unsigned short*)carve((size_t)N * FDIM * 2);  // bf16 xW
  int*            cnt   = (int*)           carve((size_t)N * 4);
  float*          dinv  = (float*)         carve((size_t)N * 4);
  int*            col   = (int*)           carve((size_t)N * CAP * 4);
  float*          gate  = (float*)         carve((size_t)N * 4);
  unsigned*       pmax  = (unsigned*)      carve(GMAX_BLOCKS * NGRAPH * 4);
  float*          denom = (float*)         carve(NGRAPH * 4);
  unsigned short* Wt1   = (unsigned short*)carve((size_t)256 * 512 * 2);
  unsigned short* Wt2   = (unsigned short*)carve((size_t)256 * 256 * 2);
  (void)ws_size; (void)n_in; (void)out_size;

  const int TB = 256;
  init_k<<<(N + TB - 1) / TB, TB, 0, stream>>>(cnt, denom, out, N);
  csr_k<<<(E + TB - 1) / TB, TB, 0, stream>>>(src, dst, cnt, col, E);
  dinv_k<<<(N + TB - 1) / TB, TB, 0, stream>>>(cnt, dinv, N);
  wconv_k<<<(512 * 256 + 256 * 256 + TB - 1) / TB, TB, 0, stream>>>(W1, W2, Wt1, Wt2);

  int gblocks = (N + 127) / 128;
  int ablocks = (N + 3) / 4;
  gemm_k<512, true ><<<gblocks, 512, 0, stream>>>(x,   Wt1, xwb, N);
  agg_k<true,  false><<<ablocks, 256, 0, stream>>>(xwb, dinv, col, cnt, b1, h1b, nullptr, nullptr, nullptr, N);
  gemm_k<256, false><<<gblocks, 512, 0, stream>>>(h1b, Wt2, xwb, N);
  agg_k<true,  true ><<<ablocks, 256, 0, stream>>>(xwb, dinv, col, cnt, b2, h, gw, gb, gate, N);

  gmax_k<<<GMAX_BLOCKS, 256, 0, stream>>>(gate, batch, pmax, N);
  denom_k<<<GMAX_BLOCKS, 256, 0, stream>>>(gate, batch, pmax, denom, N);
  final_k<<<FINAL_BLOCKS, 256, 0, stream>>>(h, gate, batch, denom, out, N);
}

// Round 13
// 226.745 us; speedup vs baseline: 1.1706x; 1.1008x over previous
//
#include <hip/hip_runtime.h>
#include <hip/hip_bf16.h>
#include <math.h>

#define FDIM 256
#define CAP 64
#define NGRAPH 8
#define GMAX_BLOCKS 64
#define FINAL_BLOCKS 512

typedef __attribute__((ext_vector_type(8))) short bf16x8;
typedef __attribute__((ext_vector_type(4))) float f32x4;
typedef __attribute__((ext_vector_type(2))) float f32x2;

__device__ __forceinline__ unsigned enc_f(float x){
  unsigned u = __float_as_uint(x);
  return (u >> 31) ? ~u : (u | 0x80000000u);
}
__device__ __forceinline__ float dec_f(unsigned u){
  return (u >> 31) ? __uint_as_float(u & 0x7FFFFFFFu) : __uint_as_float(~u);
}

__device__ __forceinline__ unsigned short f2bf(float f){
  unsigned u = __float_as_uint(f);
  unsigned r = (u + 0x7FFFu + ((u >> 16) & 1u)) >> 16;
  return (unsigned short)r;
}
__device__ __forceinline__ float bf2f(unsigned short h){
  return __uint_as_float(((unsigned)h) << 16);
}
__device__ __forceinline__ unsigned pk2(float a, float b){
  return (unsigned)f2bf(a) | ((unsigned)f2bf(b) << 16);
}
__device__ __forceinline__ unsigned char f2fp8(float v){
  unsigned p = __builtin_amdgcn_cvt_pk_fp8_f32(v, v, 0u, false);
  return (unsigned char)(p & 0xFFu);
}

// ---------------- init ----------------
__global__ void init_k(int* cnt, float* denom, float* out, int N){
  int i = blockIdx.x * blockDim.x + threadIdx.x;
  if (i < N) cnt[i] = 0;
  if (i < NGRAPH) denom[i] = 0.f;
  if (i < NGRAPH * FDIM) out[i] = 0.f;
}

// ---------------- CSR fill (capped bucket); cnt = true in-degree ----------------
__global__ void csr_k(const int* __restrict__ src, const int* __restrict__ dst,
                      int* __restrict__ cnt, int* __restrict__ col, int E){
  int e = blockIdx.x * blockDim.x + threadIdx.x;
  if (e < E){
    int d = dst[e];
    int pos = atomicAdd(&cnt[d], 1);
    if (pos < CAP) col[(size_t)d * CAP + pos] = src[e];
  }
}

// ---------------- dinv from cnt (deg = cnt + 1 self-loop) ----------------
__global__ void dinv_k(const int* __restrict__ cnt, float* __restrict__ dinv, int N){
  int i = blockIdx.x * blockDim.x + threadIdx.x;
  if (i < N) dinv[i] = rsqrtf((float)(cnt[i] + 1));
}

// ---------------- W1+W2 transpose+bf16 (merged) ----------------
__global__ void wconv_k(const float* __restrict__ W1, const float* __restrict__ W2,
                        unsigned short* __restrict__ Wt1, unsigned short* __restrict__ Wt2){
  int idx = blockIdx.x * 256 + threadIdx.x;
  if (idx < 512 * 256){
    int k = idx >> 8, n = idx & 255;
    Wt1[(size_t)n * 512 + k] = f2bf(W1[idx]);
  } else {
    int j = idx - 512 * 256;
    if (j < 256 * 256){
      int k = j >> 8, n = j & 255;
      Wt2[(size_t)n * 256 + k] = f2bf(W2[j]);
    }
  }
}

// ---------------- pure-bf16 MFMA GEMM, register-staged pipelined, fp8 output ----------------
template<int K, bool A_FP32>
__global__ __launch_bounds__(512) void gemm_k(const void* __restrict__ Av,
                                              const unsigned short* __restrict__ Bt,
                                              unsigned char* __restrict__ C, int M){
  __shared__ unsigned short As[128 * 64];   // 16 KB
  __shared__ unsigned short Bs[256 * 64];   // 32 KB
  const int tid = threadIdx.x;
  const int lane = tid & 63, wid = tid >> 6;
  const int wr = wid >> 2, wc = wid & 3;    // 2 x 4 wave grid
  const int m0 = blockIdx.x * 128;
  f32x4 acc[4][4] = {};

  float4 arf0, arf1, arf2, arf3;
  uint4  arb0, arb1;
  uint4  brg0, brg1, brg2, brg3;

  const int rA0 = tid >> 3,          kqA0 = tid & 7;
  const int rA1 = (512 + tid) >> 3,  kqA1 = tid & 7;

  auto issue = [&](int k0){
    if (A_FP32){
      const float* A = (const float*)Av;
      const float* p0 = A + (size_t)min(m0 + rA0, M - 1) * K + k0 + kqA0 * 8;
      const float* p1 = A + (size_t)min(m0 + rA1, M - 1) * K + k0 + kqA1 * 8;
      arf0 = *(const float4*)p0; arf1 = *(const float4*)(p0 + 4);
      arf2 = *(const float4*)p1; arf3 = *(const float4*)(p1 + 4);
    } else {
      const unsigned short* A = (const unsigned short*)Av;
      arb0 = *(const uint4*)(A + (size_t)min(m0 + rA0, M - 1) * K + k0 + kqA0 * 8);
      arb1 = *(const uint4*)(A + (size_t)min(m0 + rA1, M - 1) * K + k0 + kqA1 * 8);
    }
    {
      int n0 = tid >> 3, n1 = (512 + tid) >> 3, n2 = (1024 + tid) >> 3, n3 = (1536 + tid) >> 3;
      int kq = tid & 7;
      brg0 = *(const uint4*)(Bt + (size_t)n0 * K + k0 + kq * 8);
      brg1 = *(const uint4*)(Bt + (size_t)n1 * K + k0 + kq * 8);
      brg2 = *(const uint4*)(Bt + (size_t)n2 * K + k0 + kq * 8);
      brg3 = *(const uint4*)(Bt + (size_t)n3 * K + k0 + kq * 8);
    }
  };

  auto writeLDS = [&](){
    int kq = tid & 7;
    {
      uint4 u0, u1;
      if (A_FP32){
        u0.x = pk2(arf0.x, arf0.y); u0.y = pk2(arf0.z, arf0.w);
        u0.z = pk2(arf1.x, arf1.y); u0.w = pk2(arf1.z, arf1.w);
        u1.x = pk2(arf2.x, arf2.y); u1.y = pk2(arf2.z, arf2.w);
        u1.z = pk2(arf3.x, arf3.y); u1.w = pk2(arf3.z, arf3.w);
      } else { u0 = arb0; u1 = arb1; }
      *(uint4*)((char*)As + ((rA0 * 128 + kq * 16) ^ ((rA0 & 7) << 4))) = u0;
      *(uint4*)((char*)As + ((rA1 * 128 + kq * 16) ^ ((rA1 & 7) << 4))) = u1;
    }
    {
      int n0 = tid >> 3, n1 = (512 + tid) >> 3, n2 = (1024 + tid) >> 3, n3 = (1536 + tid) >> 3;
      *(uint4*)((char*)Bs + ((n0 * 128 + kq * 16) ^ ((n0 & 7) << 4))) = brg0;
      *(uint4*)((char*)Bs + ((n1 * 128 + kq * 16) ^ ((n1 & 7) << 4))) = brg1;
      *(uint4*)((char*)Bs + ((n2 * 128 + kq * 16) ^ ((n2 & 7) << 4))) = brg2;
      *(uint4*)((char*)Bs + ((n3 * 128 + kq * 16) ^ ((n3 & 7) << 4))) = brg3;
    }
  };

  issue(0);
  for (int k0 = 0; k0 < K; k0 += 64){
    writeLDS();
    __syncthreads();
    if (k0 + 64 < K) issue(k0 + 64);

    #pragma unroll
    for (int kk = 0; kk < 64; kk += 32){
      bf16x8 af[4], bfr[4];
      int kb = kk * 2 + ((lane >> 4) << 4);
      #pragma unroll
      for (int mi = 0; mi < 4; ++mi){
        int r = wr * 64 + mi * 16 + (lane & 15);
        af[mi] = *(bf16x8*)((char*)As + ((r * 128 + kb) ^ ((r & 7) << 4)));
      }
      #pragma unroll
      for (int ni = 0; ni < 4; ++ni){
        int n = wc * 64 + ni * 16 + (lane & 15);
        bfr[ni] = *(bf16x8*)((char*)Bs + ((n * 128 + kb) ^ ((n & 7) << 4)));
      }
      #pragma unroll
      for (int mi = 0; mi < 4; ++mi)
        #pragma unroll
        for (int ni = 0; ni < 4; ++ni)
          acc[mi][ni] = __builtin_amdgcn_mfma_f32_16x16x32_bf16(af[mi], bfr[ni], acc[mi][ni], 0, 0, 0);
    }
    __syncthreads();
  }

  #pragma unroll
  for (int mi = 0; mi < 4; ++mi){
    #pragma unroll
    for (int reg = 0; reg < 4; ++reg){
      int row = m0 + wr * 64 + mi * 16 + ((lane >> 4) << 2) + reg;
      if (row < M){
        #pragma unroll
        for (int ni = 0; ni < 4; ++ni){
          int colc = wc * 64 + ni * 16 + (lane & 15);
          C[(size_t)row * FDIM + colc] = f2fp8(acc[mi][ni][reg]);
        }
      }
    }
  }
}

// ---------------- aggregation: fp8 gather, 4 waves/block, 8-deep pipeline ----------------
// Wave = one node; lane covers 4 features (uint = 4 fp8); bf16 output.
template<bool GATE>
__global__ __launch_bounds__(256) void agg_k(const unsigned char* __restrict__ xw,
                                             const float* __restrict__ dinv,
                                             const int* __restrict__ col,
                                             const int* __restrict__ cnt,
                                             const float* __restrict__ bias,
                                             unsigned short* __restrict__ outb,
                                             const float* __restrict__ gw,
                                             const float* __restrict__ gb,
                                             float* __restrict__ gate, int N){
  int node = blockIdx.x * 4 + (threadIdx.x >> 6);
  if (node >= N) return;
  int lane = threadIdx.x & 63;
  float di = dinv[node];
  int n = min(cnt[node], CAP);
  int s = 0; float w = 0.f;
  if (lane < n){ s = col[(size_t)node * CAP + lane]; w = di * dinv[s]; }

  float a0, a1, a2, a3;
  {
    unsigned u = *(const unsigned*)(xw + (size_t)node * FDIM + lane * 4);
    f32x2 lo = __builtin_amdgcn_cvt_pk_f32_fp8(u, false);
    f32x2 hi = __builtin_amdgcn_cvt_pk_f32_fp8(u, true);
    float sw = di * di;
    a0 = sw * lo.x; a1 = sw * lo.y; a2 = sw * hi.x; a3 = sw * hi.y;
  }

  unsigned bufA[8], bufB[8];
  int nc = (n + 7) >> 3;            // chunks of 8 edges

  auto loadChunk = [&](unsigned (&buf)[8], int c){
    #pragma unroll
    for (int j = 0; j < 8; ++j){
      int e = c * 8 + j;
      int se = __shfl(s, e);
      buf[j] = *(const unsigned*)(xw + (size_t)se * FDIM + lane * 4);
    }
  };
  auto consChunk = [&](unsigned (&buf)[8], int c){
    #pragma unroll
    for (int j = 0; j < 8; ++j){
      int e = c * 8 + j;
      float we = __shfl(w, e);
      f32x2 lo = __builtin_amdgcn_cvt_pk_f32_fp8(buf[j], false);
      f32x2 hi = __builtin_amdgcn_cvt_pk_f32_fp8(buf[j], true);
      a0 += we * lo.x; a1 += we * lo.y;
      a2 += we * hi.x; a3 += we * hi.y;
    }
  };

  if (nc > 0) loadChunk(bufA, 0);
  for (int c = 0; c < nc; ++c){
    if (c & 1){
      if (c + 1 < nc) loadChunk(bufA, c + 1);
      consChunk(bufB, c);
    } else {
      if (c + 1 < nc) loadChunk(bufB, c + 1);
      consChunk(bufA, c);
    }
  }

  float4 bv = *(const float4*)(bias + lane * 4);
  a0 = fmaxf(a0 + bv.x, 0.f); a1 = fmaxf(a1 + bv.y, 0.f);
  a2 = fmaxf(a2 + bv.z, 0.f); a3 = fmaxf(a3 + bv.w, 0.f);
  {
    ushort4 r = make_ushort4(f2bf(a0), f2bf(a1), f2bf(a2), f2bf(a3));
    *(ushort4*)(outb + (size_t)node * FDIM + lane * 4) = r;
  }
  if (GATE){
    float4 g = *(const float4*)(gw + lane * 4);
    float val = a0 * g.x + a1 * g.y + a2 * g.z + a3 * g.w;
    #pragma unroll
    for (int off = 32; off; off >>= 1) val += __shfl_down(val, off);
    if (lane == 0) gate[node] = val + gb[0];
  }
}

// ---------------- gmax: per-block partial segment max of gate ----------------
__global__ __launch_bounds__(256) void gmax_k(const float* __restrict__ gate,
                                              const int* __restrict__ batch,
                                              unsigned* __restrict__ pmax, int N){
  __shared__ unsigned smax[NGRAPH];
  int tid = threadIdx.x;
  if (tid < NGRAPH) smax[tid] = 0u;
  __syncthreads();
  int chunk = (N + gridDim.x - 1) / gridDim.x;
  int begin = blockIdx.x * chunk;
  int end = min(begin + chunk, N);
  int curg = -1; unsigned curm = 0u;
  for (int i = begin + tid; i < end; i += 256){
    int g = batch[i];
    unsigned v = enc_f(gate[i]);
    if (g != curg){
      if (curg >= 0) atomicMax(&smax[curg], curm);
      curg = g; curm = v;
    } else if (v > curm) curm = v;
  }
  if (curg >= 0) atomicMax(&smax[curg], curm);
  __syncthreads();
  if (tid < NGRAPH) pmax[blockIdx.x * NGRAPH + tid] = smax[tid];
}

// ---------------- denom: reduce pmax, e=exp(gate-gmax), segment sum ----------------
__global__ __launch_bounds__(256) void denom_k(float* __restrict__ gate,
                                               const int* __restrict__ batch,
                                               const unsigned* __restrict__ pmax,
                                               float* __restrict__ denom, int N){
  __shared__ unsigned sge[NGRAPH];
  __shared__ float gm[NGRAPH];
  __shared__ float dsum[NGRAPH];
  int tid = threadIdx.x;
  if (tid < NGRAPH){ sge[tid] = 0u; dsum[tid] = 0.f; }
  __syncthreads();
  for (int j = tid; j < GMAX_BLOCKS * NGRAPH; j += 256)
    atomicMax(&sge[j & (NGRAPH - 1)], pmax[j]);
  __syncthreads();
  if (tid < NGRAPH){
    unsigned u = sge[tid];
    gm[tid] = (u == 0u) ? 0.f : dec_f(u);
  }
  __syncthreads();
  int chunk = (N + gridDim.x - 1) / gridDim.x;
  int begin = blockIdx.x * chunk;
  int end = min(begin + chunk, N);
  int curg = -1; float cursum = 0.f;
  for (int i = begin + tid; i < end; i += 256){
    int g = batch[i];
    float e = expf(gate[i] - gm[g]);
    gate[i] = e;
    if (g != curg){
      if (curg >= 0) atomicAdd(&dsum[curg], cursum);
      curg = g; cursum = e;
    } else cursum += e;
  }
  if (curg >= 0) atomicAdd(&dsum[curg], cursum);
  __syncthreads();
  if (tid < NGRAPH && dsum[tid] != 0.f) atomicAdd(&denom[tid], dsum[tid]);
}

// ---------------- final: out[g] += (e_i/denom_g) * h2[i], h2 in bf16 ----------------
__global__ __launch_bounds__(256) void final_k(const unsigned short* __restrict__ h,
                                               const float* __restrict__ e,
                                               const int* __restrict__ batch,
                                               const float* __restrict__ denom,
                                               float* __restrict__ out, int N){
  __shared__ float sacc[NGRAPH * FDIM];   // 8 KB
  int tid = threadIdx.x;
  #pragma unroll
  for (int j = tid; j < NGRAPH * FDIM; j += 256) sacc[j] = 0.f;
  __syncthreads();
  int lane = tid & 63, w = tid >> 6;
  int chunk = (N + gridDim.x - 1) / gridDim.x;
  int begin = blockIdx.x * chunk;
  int end = min(begin + chunk, N);
  float4 acc = make_float4(0.f, 0.f, 0.f, 0.f);
  int curg = -1;
  for (int i = begin + w; i < end; i += 4){
    int g = batch[i];
    if (g != curg){
      if (curg >= 0){
        atomicAdd(&sacc[curg * FDIM + lane * 4 + 0], acc.x);
        atomicAdd(&sacc[curg * FDIM + lane * 4 + 1], acc.y);
        atomicAdd(&sacc[curg * FDIM + lane * 4 + 2], acc.z);
        atomicAdd(&sacc[curg * FDIM + lane * 4 + 3], acc.w);
        acc = make_float4(0.f, 0.f, 0.f, 0.f);
      }
      curg = g;
    }
    float alpha = e[i] / denom[g];
    ushort4 v = *(const ushort4*)(h + (size_t)i * FDIM + lane * 4);
    acc.x += alpha * bf2f(v.x); acc.y += alpha * bf2f(v.y);
    acc.z += alpha * bf2f(v.z); acc.w += alpha * bf2f(v.w);
  }
  if (curg >= 0){
    atomicAdd(&sacc[curg * FDIM + lane * 4 + 0], acc.x);
    atomicAdd(&sacc[curg * FDIM + lane * 4 + 1], acc.y);
    atomicAdd(&sacc[curg * FDIM + lane * 4 + 2], acc.z);
    atomicAdd(&sacc[curg * FDIM + lane * 4 + 3], acc.w);
  }
  __syncthreads();
  if (begin < end){
    int g0 = batch[begin], g1 = batch[end - 1];
    for (int g = g0; g <= g1; ++g){
      float v = sacc[g * FDIM + tid];
      if (v != 0.f) atomicAdd(&out[g * FDIM + tid], v);
    }
  }
}

extern "C" void kernel_launch(void* const* d_in, const int* in_sizes, int n_in,
                              void* d_out, int out_size, void* d_ws, size_t ws_size,
                              hipStream_t stream){
  const float* x     = (const float*)d_in[0];
  const int*   ei    = (const int*)  d_in[1];
  const int*   batch = (const int*)  d_in[2];
  const float* W1    = (const float*)d_in[3];
  const float* b1    = (const float*)d_in[4];
  const float* W2    = (const float*)d_in[5];
  const float* b2    = (const float*)d_in[6];
  const float* gw    = (const float*)d_in[7];
  const float* gb    = (const float*)d_in[8];
  float* out = (float*)d_out;

  const int N = in_sizes[2];
  const int E = in_sizes[1] / 2;
  const int* src = ei;
  const int* dst = ei + E;

  size_t off = 0;
  auto carve = [&](size_t bytes) -> void* {
    void* p = (char*)d_ws + off;
    off += (bytes + 255) / 256 * 256;
    return p;
  };
  unsigned short* h     = (unsigned short*)carve((size_t)N * FDIM * 2);  // bf16 h2
  unsigned short* h1b   = (unsigned short*)carve((size_t)N * FDIM * 2);  // bf16 h1
  unsigned char*  xwb   = (unsigned char*) carve((size_t)N * FDIM);     // fp8 xW
  int*            cnt   = (int*)           carve((size_t)N * 4);
  float*          dinv  = (float*)         carve((size_t)N * 4);
  int*            col   = (int*)           carve((size_t)N * CAP * 4);
  float*          gate  = (float*)         carve((size_t)N * 4);
  unsigned*       pmax  = (unsigned*)      carve(GMAX_BLOCKS * NGRAPH * 4);
  float*          denom = (float*)         carve(NGRAPH * 4);
  unsigned short* Wt1   = (unsigned short*)carve((size_t)256 * 512 * 2);
  unsigned short* Wt2   = (unsigned short*)carve((size_t)256 * 256 * 2);
  (void)ws_size; (void)n_in; (void)out_size;

  const int TB = 256;
  init_k<<<(N + TB - 1) / TB, TB, 0, stream>>>(cnt, denom, out, N);
  csr_k<<<(E + TB - 1) / TB, TB, 0, stream>>>(src, dst, cnt, col, E);
  dinv_k<<<(N + TB - 1) / TB, TB, 0, stream>>>(cnt, dinv, N);
  wconv_k<<<(512 * 256 + 256 * 256 + TB - 1) / TB, TB, 0, stream>>>(W1, W2, Wt1, Wt2);

  int gblocks = (N + 127) / 128;
  int ablocks = (N + 3) / 4;
  gemm_k<512, true ><<<gblocks, 512, 0, stream>>>(x,   Wt1, xwb, N);
  agg_k<false><<<ablocks, 256, 0, stream>>>(xwb, dinv, col, cnt, b1, h1b, nullptr, nullptr, nullptr, N);
  gemm_k<256, false><<<gblocks, 512, 0, stream>>>(h1b, Wt2, xwb, N);
  agg_k<true ><<<ablocks, 256, 0, stream>>>(xwb, dinv, col, cnt, b2, h, gw, gb, gate, N);

  gmax_k<<<GMAX_BLOCKS, 256, 0, stream>>>(gate, batch, pmax, N);
  denom_k<<<GMAX_BLOCKS, 256, 0, stream>>>(gate, batch, pmax, denom, N);
  final_k<<<FINAL_BLOCKS, 256, 0, stream>>>(h, gate, batch, denom, out, N);
}

// Round 15
// 219.918 us; speedup vs baseline: 1.2069x; 1.0310x over previous
//
#include <hip/hip_runtime.h>
#include <hip/hip_bf16.h>
#include <math.h>

#define FDIM 256
#define CAP 64
#define NGRAPH 8
#define GMAX_BLOCKS 64
#define FINAL_BLOCKS 512

typedef __attribute__((ext_vector_type(8))) short bf16x8;
typedef __attribute__((ext_vector_type(4))) float f32x4;
typedef __attribute__((ext_vector_type(2))) float f32x2;

__device__ __forceinline__ unsigned enc_f(float x){
  unsigned u = __float_as_uint(x);
  return (u >> 31) ? ~u : (u | 0x80000000u);
}
__device__ __forceinline__ float dec_f(unsigned u){
  return (u >> 31) ? __uint_as_float(u & 0x7FFFFFFFu) : __uint_as_float(~u);
}

__device__ __forceinline__ unsigned short f2bf(float f){
  unsigned u = __float_as_uint(f);
  unsigned r = (u + 0x7FFFu + ((u >> 16) & 1u)) >> 16;
  return (unsigned short)r;
}
__device__ __forceinline__ float bf2f(unsigned short h){
  return __uint_as_float(((unsigned)h) << 16);
}
__device__ __forceinline__ unsigned pk2(float a, float b){
  return (unsigned)f2bf(a) | ((unsigned)f2bf(b) << 16);
}
__device__ __forceinline__ unsigned char f2fp8(float v){
  unsigned p = __builtin_amdgcn_cvt_pk_fp8_f32(v, v, 0u, false);
  return (unsigned char)(p & 0xFFu);
}

// ---------------- init ----------------
__global__ void init_k(int* cnt, float* denom, float* out, int N){
  int i = blockIdx.x * blockDim.x + threadIdx.x;
  if (i < N) cnt[i] = 0;
  if (i < NGRAPH) denom[i] = 0.f;
  if (i < NGRAPH * FDIM) out[i] = 0.f;
}

// ---------------- CSR fill (capped bucket); cnt = true in-degree ----------------
__global__ void csr_k(const int* __restrict__ src, const int* __restrict__ dst,
                      int* __restrict__ cnt, int* __restrict__ col, int E){
  int e = blockIdx.x * blockDim.x + threadIdx.x;
  if (e < E){
    int d = dst[e];
    int pos = atomicAdd(&cnt[d], 1);
    if (pos < CAP) col[(size_t)d * CAP + pos] = src[e];
  }
}

// ---------------- dinv from cnt (deg = cnt + 1 self-loop) ----------------
__global__ void dinv_k(const int* __restrict__ cnt, float* __restrict__ dinv, int N){
  int i = blockIdx.x * blockDim.x + threadIdx.x;
  if (i < N) dinv[i] = rsqrtf((float)(cnt[i] + 1));
}

// ---------------- W1+W2 transpose+bf16 (merged) ----------------
__global__ void wconv_k(const float* __restrict__ W1, const float* __restrict__ W2,
                        unsigned short* __restrict__ Wt1, unsigned short* __restrict__ Wt2){
  int idx = blockIdx.x * 256 + threadIdx.x;
  if (idx < 512 * 256){
    int k = idx >> 8, n = idx & 255;
    Wt1[(size_t)n * 512 + k] = f2bf(W1[idx]);
  } else {
    int j = idx - 512 * 256;
    if (j < 256 * 256){
      int k = j >> 8, n = j & 255;
      Wt2[(size_t)n * 256 + k] = f2bf(W2[j]);
    }
  }
}

// ---------------- pure-bf16 MFMA GEMM, 2-deep register-prefetch pipeline, fp8 out ----------------
// Block tile 128x256, BK=64, two K-tiles per loop iter (K % 128 == 0).
template<int K, bool A_FP32>
__global__ __launch_bounds__(512) void gemm_k(const void* __restrict__ Av,
                                              const unsigned short* __restrict__ Bt,
                                              unsigned char* __restrict__ C, int M){
  __shared__ unsigned short As[128 * 64];   // 16 KB
  __shared__ unsigned short Bs[256 * 64];   // 32 KB
  const int tid = threadIdx.x;
  const int lane = tid & 63, wid = tid >> 6;
  const int wr = wid >> 2, wc = wid & 3;    // 2 x 4 wave grid
  const int m0 = blockIdx.x * 128;
  f32x4 acc[4][4] = {};

  // two named staging sets (static indexing only — rule #20)
  float4 fa0, fa1, fa2, fa3, fb0, fb1, fb2, fb3;
  uint4  ua0, ua1, ub0, ub1;
  uint4  ba0, ba1, ba2, ba3, bb0, bb1, bb2, bb3;

  const int rA0 = tid >> 3,          kqA = tid & 7;
  const int rA1 = (512 + tid) >> 3;
  const int nB0 = tid >> 3, nB1 = (512 + tid) >> 3, nB2 = (1024 + tid) >> 3, nB3 = (1536 + tid) >> 3;

  auto issueA = [&](int k0){
    if (A_FP32){
      const float* A = (const float*)Av;
      const float* p0 = A + (size_t)min(m0 + rA0, M - 1) * K + k0 + kqA * 8;
      const float* p1 = A + (size_t)min(m0 + rA1, M - 1) * K + k0 + kqA * 8;
      fa0 = *(const float4*)p0; fa1 = *(const float4*)(p0 + 4);
      fa2 = *(const float4*)p1; fa3 = *(const float4*)(p1 + 4);
    } else {
      const unsigned short* A = (const unsigned short*)Av;
      ua0 = *(const uint4*)(A + (size_t)min(m0 + rA0, M - 1) * K + k0 + kqA * 8);
      ua1 = *(const uint4*)(A + (size_t)min(m0 + rA1, M - 1) * K + k0 + kqA * 8);
    }
    ba0 = *(const uint4*)(Bt + (size_t)nB0 * K + k0 + kqA * 8);
    ba1 = *(const uint4*)(Bt + (size_t)nB1 * K + k0 + kqA * 8);
    ba2 = *(const uint4*)(Bt + (size_t)nB2 * K + k0 + kqA * 8);
    ba3 = *(const uint4*)(Bt + (size_t)nB3 * K + k0 + kqA * 8);
  };
  auto issueB = [&](int k0){
    if (A_FP32){
      const float* A = (const float*)Av;
      const float* p0 = A + (size_t)min(m0 + rA0, M - 1) * K + k0 + kqA * 8;
      const float* p1 = A + (size_t)min(m0 + rA1, M - 1) * K + k0 + kqA * 8;
      fb0 = *(const float4*)p0; fb1 = *(const float4*)(p0 + 4);
      fb2 = *(const float4*)p1; fb3 = *(const float4*)(p1 + 4);
    } else {
      const unsigned short* A = (const unsigned short*)Av;
      ub0 = *(const uint4*)(A + (size_t)min(m0 + rA0, M - 1) * K + k0 + kqA * 8);
      ub1 = *(const uint4*)(A + (size_t)min(m0 + rA1, M - 1) * K + k0 + kqA * 8);
    }
    bb0 = *(const uint4*)(Bt + (size_t)nB0 * K + k0 + kqA * 8);
    bb1 = *(const uint4*)(Bt + (size_t)nB1 * K + k0 + kqA * 8);
    bb2 = *(const uint4*)(Bt + (size_t)nB2 * K + k0 + kqA * 8);
    bb3 = *(const uint4*)(Bt + (size_t)nB3 * K + k0 + kqA * 8);
  };

  auto writeA = [&](){
    uint4 u0, u1;
    if (A_FP32){
      u0.x = pk2(fa0.x, fa0.y); u0.y = pk2(fa0.z, fa0.w);
      u0.z = pk2(fa1.x, fa1.y); u0.w = pk2(fa1.z, fa1.w);
      u1.x = pk2(fa2.x, fa2.y); u1.y = pk2(fa2.z, fa2.w);
      u1.z = pk2(fa3.x, fa3.y); u1.w = pk2(fa3.z, fa3.w);
    } else { u0 = ua0; u1 = ua1; }
    *(uint4*)((char*)As + ((rA0 * 128 + kqA * 16) ^ ((rA0 & 7) << 4))) = u0;
    *(uint4*)((char*)As + ((rA1 * 128 + kqA * 16) ^ ((rA1 & 7) << 4))) = u1;
    *(uint4*)((char*)Bs + ((nB0 * 128 + kqA * 16) ^ ((nB0 & 7) << 4))) = ba0;
    *(uint4*)((char*)Bs + ((nB1 * 128 + kqA * 16) ^ ((nB1 & 7) << 4))) = ba1;
    *(uint4*)((char*)Bs + ((nB2 * 128 + kqA * 16) ^ ((nB2 & 7) << 4))) = ba2;
    *(uint4*)((char*)Bs + ((nB3 * 128 + kqA * 16) ^ ((nB3 & 7) << 4))) = ba3;
  };
  auto writeB = [&](){
    uint4 u0, u1;
    if (A_FP32){
      u0.x = pk2(fb0.x, fb0.y); u0.y = pk2(fb0.z, fb0.w);
      u0.z = pk2(fb1.x, fb1.y); u0.w = pk2(fb1.z, fb1.w);
      u1.x = pk2(fb2.x, fb2.y); u1.y = pk2(fb2.z, fb2.w);
      u1.z = pk2(fb3.x, fb3.y); u1.w = pk2(fb3.z, fb3.w);
    } else { u0 = ub0; u1 = ub1; }
    *(uint4*)((char*)As + ((rA0 * 128 + kqA * 16) ^ ((rA0 & 7) << 4))) = u0;
    *(uint4*)((char*)As + ((rA1 * 128 + kqA * 16) ^ ((rA1 & 7) << 4))) = u1;
    *(uint4*)((char*)Bs + ((nB0 * 128 + kqA * 16) ^ ((nB0 & 7) << 4))) = bb0;
    *(uint4*)((char*)Bs + ((nB1 * 128 + kqA * 16) ^ ((nB1 & 7) << 4))) = bb1;
    *(uint4*)((char*)Bs + ((nB2 * 128 + kqA * 16) ^ ((nB2 & 7) << 4))) = bb2;
    *(uint4*)((char*)Bs + ((nB3 * 128 + kqA * 16) ^ ((nB3 & 7) << 4))) = bb3;
  };

  auto compute = [&](){
    #pragma unroll
    for (int kk = 0; kk < 64; kk += 32){
      bf16x8 af[4], bfr[4];
      int kb = kk * 2 + ((lane >> 4) << 4);
      #pragma unroll
      for (int mi = 0; mi < 4; ++mi){
        int r = wr * 64 + mi * 16 + (lane & 15);
        af[mi] = *(bf16x8*)((char*)As + ((r * 128 + kb) ^ ((r & 7) << 4)));
      }
      #pragma unroll
      for (int ni = 0; ni < 4; ++ni){
        int n = wc * 64 + ni * 16 + (lane & 15);
        bfr[ni] = *(bf16x8*)((char*)Bs + ((n * 128 + kb) ^ ((n & 7) << 4)));
      }
      #pragma unroll
      for (int mi = 0; mi < 4; ++mi)
        #pragma unroll
        for (int ni = 0; ni < 4; ++ni)
          acc[mi][ni] = __builtin_amdgcn_mfma_f32_16x16x32_bf16(af[mi], bfr[ni], acc[mi][ni], 0, 0, 0);
    }
  };

  issueA(0);
  issueB(64);
  for (int k0 = 0; k0 < K; k0 += 128){
    writeA();                        // waits only on A-set loads
    __syncthreads();
    if (k0 + 128 < K) issueA(k0 + 128);
    compute();
    __syncthreads();
    writeB();                        // waits only on B-set loads
    __syncthreads();
    if (k0 + 192 < K) issueB(k0 + 192);
    compute();
    __syncthreads();
  }

  #pragma unroll
  for (int mi = 0; mi < 4; ++mi){
    #pragma unroll
    for (int reg = 0; reg < 4; ++reg){
      int row = m0 + wr * 64 + mi * 16 + ((lane >> 4) << 2) + reg;
      if (row < M){
        #pragma unroll
        for (int ni = 0; ni < 4; ++ni){
          int colc = wc * 64 + ni * 16 + (lane & 15);
          C[(size_t)row * FDIM + colc] = f2fp8(acc[mi][ni][reg]);
        }
      }
    }
  }
}

// ---------------- aggregation: fp8 gather, 4 waves/block, 8-deep pipeline ----------------
template<bool GATE>
__global__ __launch_bounds__(256) void agg_k(const unsigned char* __restrict__ xw,
                                             const float* __restrict__ dinv,
                                             const int* __restrict__ col,
                                             const int* __restrict__ cnt,
                                             const float* __restrict__ bias,
                                             unsigned short* __restrict__ outb,
                                             const float* __restrict__ gw,
                                             const float* __restrict__ gb,
                                             float* __restrict__ gate, int N){
  int node = blockIdx.x * 4 + (threadIdx.x >> 6);
  if (node >= N) return;
  int lane = threadIdx.x & 63;
  float di = dinv[node];
  int n = min(cnt[node], CAP);
  int s = 0; float w = 0.f;
  if (lane < n){ s = col[(size_t)node * CAP + lane]; w = di * dinv[s]; }

  float a0, a1, a2, a3;
  {
    unsigned u = *(const unsigned*)(xw + (size_t)node * FDIM + lane * 4);
    f32x2 lo = __builtin_amdgcn_cvt_pk_f32_fp8(u, false);
    f32x2 hi = __builtin_amdgcn_cvt_pk_f32_fp8(u, true);
    float sw = di * di;
    a0 = sw * lo.x; a1 = sw * lo.y; a2 = sw * hi.x; a3 = sw * hi.y;
  }

  unsigned bufA[8], bufB[8];
  int nc = (n + 7) >> 3;            // chunks of 8 edges

  auto loadChunk = [&](unsigned (&buf)[8], int c){
    #pragma unroll
    for (int j = 0; j < 8; ++j){
      int e = c * 8 + j;
      int se = __shfl(s, e);
      buf[j] = *(const unsigned*)(xw + (size_t)se * FDIM + lane * 4);
    }
  };
  auto consChunk = [&](unsigned (&buf)[8], int c){
    #pragma unroll
    for (int j = 0; j < 8; ++j){
      int e = c * 8 + j;
      float we = __shfl(w, e);
      f32x2 lo = __builtin_amdgcn_cvt_pk_f32_fp8(buf[j], false);
      f32x2 hi = __builtin_amdgcn_cvt_pk_f32_fp8(buf[j], true);
      a0 += we * lo.x; a1 += we * lo.y;
      a2 += we * hi.x; a3 += we * hi.y;
    }
  };

  if (nc > 0) loadChunk(bufA, 0);
  for (int c = 0; c < nc; ++c){
    if (c & 1){
      if (c + 1 < nc) loadChunk(bufA, c + 1);
      consChunk(bufB, c);
    } else {
      if (c + 1 < nc) loadChunk(bufB, c + 1);
      consChunk(bufA, c);
    }
  }

  float4 bv = *(const float4*)(bias + lane * 4);
  a0 = fmaxf(a0 + bv.x, 0.f); a1 = fmaxf(a1 + bv.y, 0.f);
  a2 = fmaxf(a2 + bv.z, 0.f); a3 = fmaxf(a3 + bv.w, 0.f);
  {
    ushort4 r = make_ushort4(f2bf(a0), f2bf(a1), f2bf(a2), f2bf(a3));
    *(ushort4*)(outb + (size_t)node * FDIM + lane * 4) = r;
  }
  if (GATE){
    float4 g = *(const float4*)(gw + lane * 4);
    float val = a0 * g.x + a1 * g.y + a2 * g.z + a3 * g.w;
    #pragma unroll
    for (int off = 32; off; off >>= 1) val += __shfl_down(val, off);
    if (lane == 0) gate[node] = val + gb[0];
  }
}

// ---------------- gmax: per-block partial segment max of gate ----------------
__global__ __launch_bounds__(256) void gmax_k(const float* __restrict__ gate,
                                              const int* __restrict__ batch,
                                              unsigned* __restrict__ pmax, int N){
  __shared__ unsigned smax[NGRAPH];
  int tid = threadIdx.x;
  if (tid < NGRAPH) smax[tid] = 0u;
  __syncthreads();
  int chunk = (N + gridDim.x - 1) / gridDim.x;
  int begin = blockIdx.x * chunk;
  int end = min(begin + chunk, N);
  int curg = -1; unsigned curm = 0u;
  for (int i = begin + tid; i < end; i += 256){
    int g = batch[i];
    unsigned v = enc_f(gate[i]);
    if (g != curg){
      if (curg >= 0) atomicMax(&smax[curg], curm);
      curg = g; curm = v;
    } else if (v > curm) curm = v;
  }
  if (curg >= 0) atomicMax(&smax[curg], curm);
  __syncthreads();
  if (tid < NGRAPH) pmax[blockIdx.x * NGRAPH + tid] = smax[tid];
}

// ---------------- denom: reduce pmax, e=exp(gate-gmax), segment sum ----------------
__global__ __launch_bounds__(256) void denom_k(float* __restrict__ gate,
                                               const int* __restrict__ batch,
                                               const unsigned* __restrict__ pmax,
                                               float* __restrict__ denom, int N){
  __shared__ unsigned sge[NGRAPH];
  __shared__ float gm[NGRAPH];
  __shared__ float dsum[NGRAPH];
  int tid = threadIdx.x;
  if (tid < NGRAPH){ sge[tid] = 0u; dsum[tid] = 0.f; }
  __syncthreads();
  for (int j = tid; j < GMAX_BLOCKS * NGRAPH; j += 256)
    atomicMax(&sge[j & (NGRAPH - 1)], pmax[j]);
  __syncthreads();
  if (tid < NGRAPH){
    unsigned u = sge[tid];
    gm[tid] = (u == 0u) ? 0.f : dec_f(u);
  }
  __syncthreads();
  int chunk = (N + gridDim.x - 1) / gridDim.x;
  int begin = blockIdx.x * chunk;
  int end = min(begin + chunk, N);
  int curg = -1; float cursum = 0.f;
  for (int i = begin + tid; i < end; i += 256){
    int g = batch[i];
    float e = expf(gate[i] - gm[g]);
    gate[i] = e;
    if (g != curg){
      if (curg >= 0) atomicAdd(&dsum[curg], cursum);
      curg = g; cursum = e;
    } else cursum += e;
  }
  if (curg >= 0) atomicAdd(&dsum[curg], cursum);
  __syncthreads();
  if (tid < NGRAPH && dsum[tid] != 0.f) atomicAdd(&denom[tid], dsum[tid]);
}

// ---------------- final: out[g] += (e_i/denom_g) * h2[i], h2 in bf16 ----------------
__global__ __launch_bounds__(256) void final_k(const unsigned short* __restrict__ h,
                                               const float* __restrict__ e,
                                               const int* __restrict__ batch,
                                               const float* __restrict__ denom,
                                               float* __restrict__ out, int N){
  __shared__ float sacc[NGRAPH * FDIM];   // 8 KB
  int tid = threadIdx.x;
  #pragma unroll
  for (int j = tid; j < NGRAPH * FDIM; j += 256) sacc[j] = 0.f;
  __syncthreads();
  int lane = tid & 63, w = tid >> 6;
  int chunk = (N + gridDim.x - 1) / gridDim.x;
  int begin = blockIdx.x * chunk;
  int end = min(begin + chunk, N);
  float4 acc = make_float4(0.f, 0.f, 0.f, 0.f);
  int curg = -1;
  for (int i = begin + w; i < end; i += 4){
    int g = batch[i];
    if (g != curg){
      if (curg >= 0){
        atomicAdd(&sacc[curg * FDIM + lane * 4 + 0], acc.x);
        atomicAdd(&sacc[curg * FDIM + lane * 4 + 1], acc.y);
        atomicAdd(&sacc[curg * FDIM + lane * 4 + 2], acc.z);
        atomicAdd(&sacc[curg * FDIM + lane * 4 + 3], acc.w);
        acc = make_float4(0.f, 0.f, 0.f, 0.f);
      }
      curg = g;
    }
    float alpha = e[i] / denom[g];
    ushort4 v = *(const ushort4*)(h + (size_t)i * FDIM + lane * 4);
    acc.x += alpha * bf2f(v.x); acc.y += alpha * bf2f(v.y);
    acc.z += alpha * bf2f(v.z); acc.w += alpha * bf2f(v.w);
  }
  if (curg >= 0){
    atomicAdd(&sacc[curg * FDIM + lane * 4 + 0], acc.x);
    atomicAdd(&sacc[curg * FDIM + lane * 4 + 1], acc.y);
    atomicAdd(&sacc[curg * FDIM + lane * 4 + 2], acc.z);
    atomicAdd(&sacc[curg * FDIM + lane * 4 + 3], acc.w);
  }
  __syncthreads();
  if (begin < end){
    int g0 = batch[begin], g1 = batch[end - 1];
    for (int g = g0; g <= g1; ++g){
      float v = sacc[g * FDIM + tid];
      if (v != 0.f) atomicAdd(&out[g * FDIM + tid], v);
    }
  }
}

extern "C" void kernel_launch(void* const* d_in, const int* in_sizes, int n_in,
                              void* d_out, int out_size, void* d_ws, size_t ws_size,
                              hipStream_t stream){
  const float* x     = (const float*)d_in[0];
  const int*   ei    = (const int*)  d_in[1];
  const int*   batch = (const int*)  d_in[2];
  const float* W1    = (const float*)d_in[3];
  const float* b1    = (const float*)d_in[4];
  const float* W2    = (const float*)d_in[5];
  const float* b2    = (const float*)d_in[6];
  const float* gw    = (const float*)d_in[7];
  const float* gb    = (const float*)d_in[8];
  float* out = (float*)d_out;

  const int N = in_sizes[2];
  const int E = in_sizes[1] / 2;
  const int* src = ei;
  const int* dst = ei + E;

  size_t off = 0;
  auto carve = [&](size_t bytes) -> void* {
    void* p = (char*)d_ws + off;
    off += (bytes + 255) / 256 * 256;
    return p;
  };
  unsigned short* h     = (unsigned short*)carve((size_t)N * FDIM * 2);  // bf16 h2
  unsigned short* h1b   = (unsigned short*)carve((size_t)N * FDIM * 2);  // bf16 h1
  unsigned char*  xwb   = (unsigned char*) carve((size_t)N * FDIM);     // fp8 xW
  int*            cnt   = (int*)           carve((size_t)N * 4);
  float*          dinv  = (float*)         carve((size_t)N * 4);
  int*            col   = (int*)           carve((size_t)N * CAP * 4);
  float*          gate  = (float*)         carve((size_t)N * 4);
  unsigned*       pmax  = (unsigned*)      carve(GMAX_BLOCKS * NGRAPH * 4);
  float*          denom = (float*)         carve(NGRAPH * 4);
  unsigned short* Wt1   = (unsigned short*)carve((size_t)256 * 512 * 2);
  unsigned short* Wt2   = (unsigned short*)carve((size_t)256 * 256 * 2);
  (void)ws_size; (void)n_in; (void)out_size;

  const int TB = 256;
  init_k<<<(N + TB - 1) / TB, TB, 0, stream>>>(cnt, denom, out, N);
  csr_k<<<(E + TB - 1) / TB, TB, 0, stream>>>(src, dst, cnt, col, E);
  dinv_k<<<(N + TB - 1) / TB, TB, 0, stream>>>(cnt, dinv, N);
  wconv_k<<<(512 * 256 + 256 * 256 + TB - 1) / TB, TB, 0, stream>>>(W1, W2, Wt1, Wt2);

  int gblocks = (N + 127) / 128;
  int ablocks = (N + 3) / 4;
  gemm_k<512, true ><<<gblocks, 512, 0, stream>>>(x,   Wt1, xwb, N);
  agg_k<false><<<ablocks, 256, 0, stream>>>(xwb, dinv, col, cnt, b1, h1b, nullptr, nullptr, nullptr, N);
  gemm_k<256, false><<<gblocks, 512, 0, stream>>>(h1b, Wt2, xwb, N);
  agg_k<true ><<<ablocks, 256, 0, stream>>>(xwb, dinv, col, cnt, b2, h, gw, gb, gate, N);

  gmax_k<<<GMAX_BLOCKS, 256, 0, stream>>>(gate, batch, pmax, N);
  denom_k<<<GMAX_BLOCKS, 256, 0, stream>>>(gate, batch, pmax, denom, N);
  final_k<<<FINAL_BLOCKS, 256, 0, stream>>>(h, gate, batch, denom, out, N);
}